// Round 1
// baseline (222.236 us; speedup 1.0000x reference)
//
#include <hip/hip_runtime.h>
#include <hip/hip_bf16.h>
#include <cstdint>
#include <cstddef>

#define C_CH 128
#define L_LEN 16384
#define B_N 8
#define K_T 3
#define EPS 1e-5f

typedef __attribute__((ext_vector_type(8))) short short8;
typedef __attribute__((ext_vector_type(4))) float float4v;

__device__ __forceinline__ short f2bf(float f) {
  union { float f; unsigned u; } v; v.f = f;
  unsigned r = v.u + 0x7fffu + ((v.u >> 16) & 1u);  // round-to-nearest-even
  return (short)(r >> 16);
}

// ---------------- Kernel A: repack dc_w [C_out, C_in, K] fp32 -> Wp[o][j] bf16, j = kt*128 + c
__global__ void repack_w(const float* __restrict__ dc_w, short* __restrict__ Wp) {
  int tid = blockIdx.x * 256 + threadIdx.x;     // 128*384 = 49152 total
  if (tid >= C_CH * C_CH * K_T) return;
  int o = tid / (C_CH * K_T);
  int j = tid % (C_CH * K_T);
  int kt = j >> 7;
  int c = j & 127;
  Wp[tid] = f2bf(dc_w[(o * C_CH + c) * K_T + kt]);
}

// ---------------- Kernel B: depthwise conv + LayerNorm + ReLU + offset linear
// offs layout: [B][K][L] for coalesced reads in the GEMM kernel.
__global__ void offsets_k(const float* __restrict__ x, const float* __restrict__ dw_w,
                          const float* __restrict__ dw_b, const float* __restrict__ ln_g,
                          const float* __restrict__ ln_b, const float* __restrict__ off_w,
                          const float* __restrict__ off_b, float* __restrict__ offs) {
  int tid = blockIdx.x * 256 + threadIdx.x;     // B*L = 131072 threads
  int b = tid >> 14;                            // L = 2^14
  int l = tid & (L_LEN - 1);
  const float* xb = x + (size_t)b * C_CH * L_LEN;
  int lm = l > 0 ? l - 1 : 0;
  int lp = l < L_LEN - 1 ? l + 1 : l;
  float mL = l > 0 ? 1.f : 0.f;
  float mR = l < L_LEN - 1 ? 1.f : 0.f;

  float sum = 0.f, sumsq = 0.f;
  for (int c = 0; c < C_CH; ++c) {
    const float* xr = xb + (size_t)c * L_LEN;
    float y = dw_b[c] + mL * xr[lm] * dw_w[c * 3]
                      + xr[l] * dw_w[c * 3 + 1]
                      + mR * xr[lp] * dw_w[c * 3 + 2];
    sum += y;
    sumsq += y * y;
  }
  float mean = sum * (1.f / C_CH);
  float var = sumsq * (1.f / C_CH) - mean * mean;
  float rstd = rsqrtf(var + EPS);

  float o0 = off_b[0], o1 = off_b[1], o2 = off_b[2];
  for (int c = 0; c < C_CH; ++c) {
    const float* xr = xb + (size_t)c * L_LEN;
    float y = dw_b[c] + mL * xr[lm] * dw_w[c * 3]
                      + xr[l] * dw_w[c * 3 + 1]
                      + mR * xr[lp] * dw_w[c * 3 + 2];
    float yn = (y - mean) * rstd * ln_g[c] + ln_b[c];
    float yr = yn > 0.f ? yn : 0.f;
    o0 += yr * off_w[c];
    o1 += yr * off_w[C_CH + c];
    o2 += yr * off_w[2 * C_CH + c];
  }
  size_t base = (size_t)b * K_T * L_LEN + l;
  offs[base] = o0;
  offs[base + L_LEN] = o1;
  offs[base + 2 * L_LEN] = o2;
}

// ---------------- Kernel C: deformable conv as fused gather + bf16 MFMA GEMM
// out[b,o,l] = sum_j Wp[o][j] * G[j][l],  j = kt*128+c,
// G[j][l] = wa[l,kt]*x[c,i0[l,kt]] + wb[l,kt]*x[c,i1[l,kt]]
// Block: 256 thr (4 waves), tile = 128 (all o) x 64 (l). K-loop: 12 steps of 32.
__global__ __launch_bounds__(256) void deform_gemm(
    const float* __restrict__ x, const float* __restrict__ offs,
    const short* __restrict__ Wp, float* __restrict__ out) {
  __shared__ float s_wa[K_T][64];
  __shared__ float s_wb[K_T][64];
  __shared__ int s_i0[K_T][64];
  __shared__ int s_i1[K_T][64];
  __shared__ short s_g[64 * 40];    // G tile [n=64][k=32], row stride 40 (16B-aligned, 2-way banks)

  int t = threadIdx.x;
  int b = blockIdx.y;
  int l0 = blockIdx.x * 64;
  const float* xb = x + (size_t)b * C_CH * L_LEN;

  // interp descriptors for this l-tile (64 n x 3 taps)
  if (t < 192) {
    int n = t & 63, kt = t >> 6;
    int l = l0 + n;
    float off = offs[((size_t)b * K_T + kt) * L_LEN + l];
    float pos = (float)(l + kt - 1) + off;
    float p0f = floorf(pos);
    float fr = pos - p0f;
    int i0 = (int)p0f;
    int i1 = i0 + 1;
    float wa = (i0 >= 0 && i0 < L_LEN) ? (1.f - fr) : 0.f;
    float wb = (i1 >= 0 && i1 < L_LEN) ? fr : 0.f;
    int i0c = i0 < 0 ? 0 : (i0 > L_LEN - 1 ? L_LEN - 1 : i0);
    int i1c = i1 < 0 ? 0 : (i1 > L_LEN - 1 ? L_LEN - 1 : i1);
    s_wa[kt][n] = wa;
    s_wb[kt][n] = wb;
    s_i0[kt][n] = i0c;
    s_i1[kt][n] = i1c;
  }
  __syncthreads();

  int lane = t & 63;
  int w = t >> 6;          // wave id: handles output rows [w*32, w*32+32)
  int n = t & 63;          // G-build: row n
  int qw = w;              // G-build: k-octet = wave id
  int qk = lane >> 4;      // MFMA quad
  int hrow = lane & 15;

  float4v acc[2][4];
  #pragma unroll
  for (int i = 0; i < 2; ++i)
    #pragma unroll
    for (int j = 0; j < 4; ++j)
      acc[i][j] = (float4v){0.f, 0.f, 0.f, 0.f};

  const short* wpa = Wp + (size_t)(w * 32 + hrow) * 384 + qk * 8;

  for (int ks = 0; ks < 12; ++ks) {
    int kt = ks >> 2;                      // tap index for this K-step
    int cb = (ks & 3) * 32 + qw * 8;       // base input channel for this thread's octet
    float wa = s_wa[kt][n], wb = s_wb[kt][n];
    const float* p0 = xb + (size_t)cb * L_LEN + s_i0[kt][n];
    const float* p1 = xb + (size_t)cb * L_LEN + s_i1[kt][n];
    short8 v;
    #pragma unroll
    for (int i = 0; i < 8; ++i) {
      float g = wa * p0[0] + wb * p1[0];
      v[i] = f2bf(g);
      p0 += L_LEN;
      p1 += L_LEN;
    }
    __syncthreads();   // previous step's MFMA ds_reads done before overwrite
    *(short8*)(s_g + n * 40 + qw * 8) = v;
    __syncthreads();   // G tile visible

    short8 a0 = *(const short8*)(wpa + ks * 32);
    short8 a1 = *(const short8*)(wpa + 16 * 384 + ks * 32);
    #pragma unroll
    for (int nt = 0; nt < 4; ++nt) {
      short8 bf = *(const short8*)(s_g + (nt * 16 + hrow) * 40 + qk * 8);
      acc[0][nt] = __builtin_amdgcn_mfma_f32_16x16x32_bf16(a0, bf, acc[0][nt], 0, 0, 0);
      acc[1][nt] = __builtin_amdgcn_mfma_f32_16x16x32_bf16(a1, bf, acc[1][nt], 0, 0, 0);
    }
  }

  // epilogue: C/D layout col=lane&15, row=(lane>>4)*4+reg
  float* ob = out + (size_t)b * C_CH * L_LEN + l0;
  #pragma unroll
  for (int mt = 0; mt < 2; ++mt) {
    int o = w * 32 + mt * 16 + qk * 4;
    #pragma unroll
    for (int nt = 0; nt < 4; ++nt) {
      int lcol = nt * 16 + hrow;
      #pragma unroll
      for (int r = 0; r < 4; ++r) {
        ob[(size_t)(o + r) * L_LEN + lcol] = acc[mt][nt][r];
      }
    }
  }
}

extern "C" void kernel_launch(void* const* d_in, const int* in_sizes, int n_in,
                              void* d_out, int out_size, void* d_ws, size_t ws_size,
                              hipStream_t stream) {
  const float* x    = (const float*)d_in[0];
  const float* dw_w = (const float*)d_in[1];
  const float* dw_b = (const float*)d_in[2];
  const float* ln_g = (const float*)d_in[3];
  const float* ln_b = (const float*)d_in[4];
  const float* off_w = (const float*)d_in[5];
  const float* off_b = (const float*)d_in[6];
  const float* dc_w = (const float*)d_in[7];
  float* out = (float*)d_out;

  float* offs = (float*)d_ws;                                        // B*K*L fp32 = 1.5 MB
  short* Wp = (short*)((char*)d_ws + (size_t)B_N * K_T * L_LEN * 4); // 128*384 bf16 = 96 KB

  hipLaunchKernelGGL(repack_w, dim3(192), dim3(256), 0, stream, dc_w, Wp);
  hipLaunchKernelGGL(offsets_k, dim3((B_N * L_LEN) / 256), dim3(256), 0, stream,
                     x, dw_w, dw_b, ln_g, ln_b, off_w, off_b, offs);
  hipLaunchKernelGGL(deform_gemm, dim3(L_LEN / 64, B_N), dim3(256), 0, stream,
                     x, offs, Wp, out);
}